// Round 1
// 280.034 us; speedup vs baseline: 1.0589x; 1.0589x over previous
//
#include <hip/hip_runtime.h>

#define HALF 128
#define NMAT 16384   // 128*128
#define NTOK 131072  // 32*4096

typedef float f4 __attribute__((ext_vector_type(4)));

// ---------------------------------------------------------------------------
// K1: fused Cayley -> QT.  Q^T = N^{-1}(2I - N) = 2 N^{-1} - I,  N = I + A/2.
// BLOCKED Gauss-Jordan (panel b=16): 8 block-steps x 2 barriers.  UNCHANGED
// from the verified round (proven numerics, latency-structural).
// ---------------------------------------------------------------------------
__global__ __launch_bounds__(512) void cayley_qt(const float* __restrict__ prim,
                                                 float* __restrict__ QT) {
    __shared__ __align__(16) float Xs[128 * 129];     // padded input stage
    __shared__ __align__(16) float CpT[2][16][132];   // panel cols, [m][r]
    __shared__ __align__(16) float Rp [2][16][128];   // panel rows, [j][c]
    __shared__ __align__(16) float Dcol[2][16][20];   // Dcol[j][m] = Dinv[m][j]

    const int b = blockIdx.x;
    const float* __restrict__ X = prim + b * NMAT;
    const int t  = threadIdx.x;
    const int c  = t & 127;          // owned column
    const int q  = t >> 7;           // row quarter (wave-uniform)
    const int r0 = q << 5;           // owns rows r0..r0+31

    for (int idx4 = t; idx4 < 4096; idx4 += 512) {
        int gi = idx4 << 2;
        float4 v = *(const float4*)(X + gi);
        int r = gi >> 7, cc = gi & 127;
        float* p = &Xs[r * 129 + cc];
        p[0] = v.x; p[1] = v.y; p[2] = v.z; p[3] = v.w;
    }
    __syncthreads();

    // reg[i] = N[r0+i][c];  A = tril(X) - tril(X)^T
    float reg[32];
    #pragma unroll
    for (int i = 0; i < 32; ++i) {
        int r  = r0 + i;
        int mx = r > c ? r : c;
        int mn = r ^ c ^ mx;
        float x = Xs[mx * 129 + mn];
        reg[i] = (r == c) ? 1.0f : (r > c ? 0.5f * x : -0.5f * x);
    }

    #pragma unroll
    for (int s = 0; s < 8; ++s) {
        const int  p     = s & 1;
        const int  k0    = s << 4;
        const int  q0    = s >> 1;          // quarter holding rows K
        const int  kl    = (s & 1) << 4;    // local row index of k0 in that quarter
        const bool panel = (c >= k0) && (c < k0 + 16);

        if (panel) {
            const int m = c - k0;
            #pragma unroll
            for (int i = 0; i < 32; i += 4)
                *(float4*)&CpT[p][m][r0 + i] =
                    make_float4(reg[i], reg[i+1], reg[i+2], reg[i+3]);
        }
        if (q == q0) {
            #pragma unroll
            for (int j = 0; j < 16; ++j) Rp[p][j][c] = reg[kl + j];
        }
        __syncthreads();

        if (t < 64) {
            const int cp = t & 15, q4 = t >> 4;
            float dd[4];
            #pragma unroll
            for (int i = 0; i < 4; ++i) dd[i] = Rp[p][q4 * 4 + i][k0 + cp];
            #pragma unroll
            for (int k = 0; k < 16; ++k) {
                float cv[4];
                #pragma unroll
                for (int i = 0; i < 4; ++i) cv[i] = __shfl(dd[i], (q4 << 4) | k);
                float rv   = __shfl(dd[k & 3], ((k >> 2) << 4) | cp);
                float dkk  = __shfl(rv, k);
                float dinv = 1.0f / dkk;
                float sv   = rv * dinv;
                bool  own  = (cp == k);
                float rf   = own ? dinv : sv;
                #pragma unroll
                for (int i = 0; i < 4; ++i)
                    dd[i] = own ? (-dd[i] * dinv) : fmaf(-cv[i], sv, dd[i]);
                dd[k & 3] = (q4 == (k >> 2)) ? rf : dd[k & 3];
            }
            #pragma unroll
            for (int i = 0; i < 4; ++i) Dcol[p][cp][q4 * 4 + i] = dd[i];
        }
        __syncthreads();

        float coeff[16];
        if (!panel) {
            #pragma unroll
            for (int j = 0; j < 16; ++j) coeff[j] = 0.0f;
            #pragma unroll
            for (int j = 0; j < 16; ++j) {
                float rpj = Rp[p][j][c];
                #pragma unroll
                for (int mq = 0; mq < 16; mq += 4) {
                    float4 dv = *(const float4*)&Dcol[p][j][mq];
                    coeff[mq+0] = fmaf(dv.x, rpj, coeff[mq+0]);
                    coeff[mq+1] = fmaf(dv.y, rpj, coeff[mq+1]);
                    coeff[mq+2] = fmaf(dv.z, rpj, coeff[mq+2]);
                    coeff[mq+3] = fmaf(dv.w, rpj, coeff[mq+3]);
                }
            }
        } else {
            const int mp = c - k0;
            #pragma unroll
            for (int j = 0; j < 16; ++j) coeff[j] = Dcol[p][mp][j];
            #pragma unroll
            for (int i = 0; i < 32; ++i) reg[i] = 0.0f;
        }

        #pragma unroll
        for (int m = 0; m < 16; ++m) {
            float cm = coeff[m];
            #pragma unroll
            for (int i = 0; i < 32; i += 4) {
                float4 c4 = *(const float4*)&CpT[p][m][r0 + i];
                reg[i+0] = fmaf(-c4.x, cm, reg[i+0]);
                reg[i+1] = fmaf(-c4.y, cm, reg[i+1]);
                reg[i+2] = fmaf(-c4.z, cm, reg[i+2]);
                reg[i+3] = fmaf(-c4.w, cm, reg[i+3]);
            }
        }
        if (q == q0) {
            #pragma unroll
            for (int j = 0; j < 16; ++j) reg[kl + j] = coeff[j];
        }
    }

    float* __restrict__ out = QT + b * NMAT;
    #pragma unroll
    for (int i = 0; i < 32; ++i) {
        int r = r0 + i;
        out[r * HALF + c] = 2.0f * reg[i] - (r == c ? 1.0f : 0.0f);
    }
}

// ---------------------------------------------------------------------------
// K2a: rows [0,256) from identity, steps d=0..6.  Re-parallelized: 64 blocks,
// 4 rows/block, 64 lanes per row with float2 column chunks (same ascending-cc
// fma association per output column -> bit-identical to the verified kernel).
// vs[rg] is touched only by its own wave; barrier kept for the proven pattern.
// ---------------------------------------------------------------------------
__global__ __launch_bounds__(256) void path_base(const float* __restrict__ QT,
                                                 const float* __restrict__ ident,
                                                 float* __restrict__ P) {
    __shared__ __align__(16) float vs[2][4][HALF];
    const int t    = threadIdx.x;
    const int rg   = t >> 6;                 // row in block (0..3), one wave each
    const int jj   = (t & 63) << 1;          // 2-col chunk
    const int v    = (blockIdx.x << 2) + rg;
    const int vmax = (blockIdx.x << 2) + 3;

    float2 cv = *(const float2*)&ident[jj];
    *(float2*)&vs[0][rg][jj] = cv;
    __syncthreads();

    int cur = 0;
    for (int d = 0; d < 8; ++d) {
        if ((vmax >> (d + 1)) == 0) break;           // block-uniform
        const bool valid = (v >> (d + 1)) > 0;
        const float* __restrict__ Qm = QT + (((v >> d) & 1) ? NMAT : 0);
        float2 acc = make_float2(0.f, 0.f);
        #pragma unroll 4
        for (int cc = 0; cc < 128; cc += 4) {
            float4 v4 = *(const float4*)&vs[cur][rg][cc];
            float2 q0 = *(const float2*)&Qm[(cc+0)*HALF + jj];
            float2 q1 = *(const float2*)&Qm[(cc+1)*HALF + jj];
            float2 q2 = *(const float2*)&Qm[(cc+2)*HALF + jj];
            float2 q3 = *(const float2*)&Qm[(cc+3)*HALF + jj];
            acc.x = fmaf(v4.x,q0.x, fmaf(v4.y,q1.x, fmaf(v4.z,q2.x, fmaf(v4.w,q3.x, acc.x))));
            acc.y = fmaf(v4.x,q0.y, fmaf(v4.y,q1.y, fmaf(v4.z,q2.y, fmaf(v4.w,q3.y, acc.y))));
        }
        if (valid) cv = acc;
        *(float2*)&vs[cur ^ 1][rg][jj] = cv;
        __syncthreads();
        cur ^= 1;
    }
    *(float2*)&P[v * HALF + jj] = cv;
}

// ---------------------------------------------------------------------------
// K2b: rows [256,4096) grouped by k (v = r | (k<<7), 8 residues r per block).
// All rows in a block share the bit-suffix: (v>>d)&1 == (k>>(d-7))&1, so each
// step needs ONE Q matrix -> staged once into LDS (64 KB) and read as
// conflict-free ds_read_b128.  L2 Q-traffic: 810 MB -> ~100 MB (8x).
// Uniform bitlen per block -> no carry-select, no per-row break.
// ---------------------------------------------------------------------------
__global__ __launch_bounds__(256) void path_upper(const float* __restrict__ QT,
                                                  float* __restrict__ P) {
    __shared__ __align__(16) float Qs[128 * 128];    // 64 KB staged matrix
    __shared__ __align__(16) float vs[8][HALF];      // row broadcast (rg-private)
    const int t  = threadIdx.x;
    const int rg = t >> 5;                 // 8 rows/block, 32 lanes each
    const int jj = (t & 31) << 2;          // 4-col chunk
    const int k  = 2 + (blockIdx.x >> 4);  // 30 k-values x 16 blocks = 480
    const int r  = ((blockIdx.x & 15) << 3) + rg;
    const int v  = (k << 7) | r;

    // ancestor: bitlen-8 row 128+r (written by path_base)
    float4 cv = *(const float4*)&P[(128 + r) * HALF + jj];

    for (int d = 7; d < 13; ++d) {
        if ((k >> (d - 6)) == 0) break;              // block-uniform
        const float* __restrict__ Qm = QT + (((k >> (d - 7)) & 1) ? NMAT : 0);
        *(float4*)&vs[rg][jj] = cv;                  // rg-private slot
        __syncthreads();                             // prev compute done (Qs free)
        for (int i = t; i < 4096; i += 256)
            *(float4*)&Qs[i << 2] = *(const float4*)&Qm[i << 2];
        __syncthreads();                             // Qs ready

        float4 acc = make_float4(0.f, 0.f, 0.f, 0.f);
        #pragma unroll 4
        for (int cc = 0; cc < 128; cc += 4) {
            float4 v4 = *(const float4*)&vs[rg][cc];          // broadcast
            float4 q0 = *(const float4*)&Qs[(cc+0)*HALF + jj];
            float4 q1 = *(const float4*)&Qs[(cc+1)*HALF + jj];
            float4 q2 = *(const float4*)&Qs[(cc+2)*HALF + jj];
            float4 q3 = *(const float4*)&Qs[(cc+3)*HALF + jj];
            acc.x = fmaf(v4.x,q0.x, fmaf(v4.y,q1.x, fmaf(v4.z,q2.x, fmaf(v4.w,q3.x, acc.x))));
            acc.y = fmaf(v4.x,q0.y, fmaf(v4.y,q1.y, fmaf(v4.z,q2.y, fmaf(v4.w,q3.y, acc.y))));
            acc.z = fmaf(v4.x,q0.z, fmaf(v4.y,q1.z, fmaf(v4.z,q2.z, fmaf(v4.w,q3.z, acc.z))));
            acc.w = fmaf(v4.x,q0.w, fmaf(v4.y,q1.w, fmaf(v4.z,q2.w, fmaf(v4.w,q3.w, acc.w))));
        }
        cv = acc;
    }
    *(float4*)&P[v * HALF + jj] = cv;
}

// ---------------------------------------------------------------------------
// K3: emit [B,S,256] = content ++ pos.  Nontemporal output stores: the 128 MiB
// write is never re-read; bypassing L2 keeps the P table hot for the gathers.
// ---------------------------------------------------------------------------
__global__ __launch_bounds__(256) void emit_out(const int* __restrict__ tt,
                                                const int* __restrict__ tv,
                                                const int* __restrict__ np,
                                                const float* __restrict__ P,
                                                const float* __restrict__ emb,
                                                float* __restrict__ out) {
    const int i  = (blockIdx.x << 2) + (threadIdx.x >> 6);
    const int jj = (threadIdx.x & 63) << 2;
    const int ty = tt[i];
    const int v  = tv[i];
    f4 val;
    if (jj < 128) {
        if (ty == 0)      val = *(const f4*)&emb[jj];
        else if (ty == 1) val = *(const f4*)&emb[(v + 1) * HALF + jj];
        else if (ty == 2) val = *(const f4*)&emb[(v + 5) * HALF + jj];
        else if (ty == 4) {
            int vc = v < 0 ? 0 : (v > 4095 ? 4095 : v);
            val = *(const f4*)&P[vc * HALF + jj];
        } else if (v == -1) val = *(const f4*)&emb[10 * HALF + jj];
        else { f4 z = {0.f, 0.f, 0.f, 0.f}; val = z; }
    } else {
        const int p = np[i];
        val = *(const f4*)&P[p * HALF + (jj - 128)];
    }
    __builtin_nontemporal_store(val, (f4*)&out[i * 256 + jj]);
}

extern "C" void kernel_launch(void* const* d_in, const int* in_sizes, int n_in,
                              void* d_out, int out_size, void* d_ws, size_t ws_size,
                              hipStream_t stream) {
    const int*   token_types = (const int*)  d_in[0];
    const int*   token_vals  = (const int*)  d_in[1];
    const int*   node_pos    = (const int*)  d_in[2];
    const float* prim        = (const float*)d_in[3];
    const float* ident       = (const float*)d_in[4];
    const float* emb         = (const float*)d_in[5];
    float* out = (float*)d_out;

    // workspace: QT[2][128][128] | (gap) | P[4096][128]
    float* QT = (float*)d_ws;
    float* P  = (float*)((char*)d_ws + 262144);

    cayley_qt  <<<2,   512, 0, stream>>>(prim, QT);
    path_base  <<<64,  256, 0, stream>>>(QT, ident, P);     // rows [0,256)
    path_upper <<<480, 256, 0, stream>>>(QT, P);            // rows [256,4096)
    emit_out   <<<NTOK / 4, 256, 0, stream>>>(token_types, token_vals, node_pos,
                                              P, emb, out);
}

// Round 2
// 275.737 us; speedup vs baseline: 1.0754x; 1.0156x over previous
//
#include <hip/hip_runtime.h>

#define HALF 128
#define NMAT 16384   // 128*128
#define NTOK 131072  // 32*4096

typedef float f4 __attribute__((ext_vector_type(4)));

// ---------------------------------------------------------------------------
// K1: fused Cayley -> QT.  Q^T = N^{-1}(2I - N) = 2 N^{-1} - I,  N = I + A/2.
// BLOCKED Gauss-Jordan (panel b=16): 8 block-steps x 2 barriers.  UNCHANGED
// (proven numerics, latency-structural).
// ---------------------------------------------------------------------------
__global__ __launch_bounds__(512) void cayley_qt(const float* __restrict__ prim,
                                                 float* __restrict__ QT) {
    __shared__ __align__(16) float Xs[128 * 129];     // padded input stage
    __shared__ __align__(16) float CpT[2][16][132];   // panel cols, [m][r]
    __shared__ __align__(16) float Rp [2][16][128];   // panel rows, [j][c]
    __shared__ __align__(16) float Dcol[2][16][20];   // Dcol[j][m] = Dinv[m][j]

    const int b = blockIdx.x;
    const float* __restrict__ X = prim + b * NMAT;
    const int t  = threadIdx.x;
    const int c  = t & 127;          // owned column
    const int q  = t >> 7;           // row quarter (wave-uniform)
    const int r0 = q << 5;           // owns rows r0..r0+31

    for (int idx4 = t; idx4 < 4096; idx4 += 512) {
        int gi = idx4 << 2;
        float4 v = *(const float4*)(X + gi);
        int r = gi >> 7, cc = gi & 127;
        float* p = &Xs[r * 129 + cc];
        p[0] = v.x; p[1] = v.y; p[2] = v.z; p[3] = v.w;
    }
    __syncthreads();

    // reg[i] = N[r0+i][c];  A = tril(X) - tril(X)^T
    float reg[32];
    #pragma unroll
    for (int i = 0; i < 32; ++i) {
        int r  = r0 + i;
        int mx = r > c ? r : c;
        int mn = r ^ c ^ mx;
        float x = Xs[mx * 129 + mn];
        reg[i] = (r == c) ? 1.0f : (r > c ? 0.5f * x : -0.5f * x);
    }

    #pragma unroll
    for (int s = 0; s < 8; ++s) {
        const int  p     = s & 1;
        const int  k0    = s << 4;
        const int  q0    = s >> 1;          // quarter holding rows K
        const int  kl    = (s & 1) << 4;    // local row index of k0 in that quarter
        const bool panel = (c >= k0) && (c < k0 + 16);

        if (panel) {
            const int m = c - k0;
            #pragma unroll
            for (int i = 0; i < 32; i += 4)
                *(float4*)&CpT[p][m][r0 + i] =
                    make_float4(reg[i], reg[i+1], reg[i+2], reg[i+3]);
        }
        if (q == q0) {
            #pragma unroll
            for (int j = 0; j < 16; ++j) Rp[p][j][c] = reg[kl + j];
        }
        __syncthreads();

        if (t < 64) {
            const int cp = t & 15, q4 = t >> 4;
            float dd[4];
            #pragma unroll
            for (int i = 0; i < 4; ++i) dd[i] = Rp[p][q4 * 4 + i][k0 + cp];
            #pragma unroll
            for (int k = 0; k < 16; ++k) {
                float cv[4];
                #pragma unroll
                for (int i = 0; i < 4; ++i) cv[i] = __shfl(dd[i], (q4 << 4) | k);
                float rv   = __shfl(dd[k & 3], ((k >> 2) << 4) | cp);
                float dkk  = __shfl(rv, k);
                float dinv = 1.0f / dkk;
                float sv   = rv * dinv;
                bool  own  = (cp == k);
                float rf   = own ? dinv : sv;
                #pragma unroll
                for (int i = 0; i < 4; ++i)
                    dd[i] = own ? (-dd[i] * dinv) : fmaf(-cv[i], sv, dd[i]);
                dd[k & 3] = (q4 == (k >> 2)) ? rf : dd[k & 3];
            }
            #pragma unroll
            for (int i = 0; i < 4; ++i) Dcol[p][cp][q4 * 4 + i] = dd[i];
        }
        __syncthreads();

        float coeff[16];
        if (!panel) {
            #pragma unroll
            for (int j = 0; j < 16; ++j) coeff[j] = 0.0f;
            #pragma unroll
            for (int j = 0; j < 16; ++j) {
                float rpj = Rp[p][j][c];
                #pragma unroll
                for (int mq = 0; mq < 16; mq += 4) {
                    float4 dv = *(const float4*)&Dcol[p][j][mq];
                    coeff[mq+0] = fmaf(dv.x, rpj, coeff[mq+0]);
                    coeff[mq+1] = fmaf(dv.y, rpj, coeff[mq+1]);
                    coeff[mq+2] = fmaf(dv.z, rpj, coeff[mq+2]);
                    coeff[mq+3] = fmaf(dv.w, rpj, coeff[mq+3]);
                }
            }
        } else {
            const int mp = c - k0;
            #pragma unroll
            for (int j = 0; j < 16; ++j) coeff[j] = Dcol[p][mp][j];
            #pragma unroll
            for (int i = 0; i < 32; ++i) reg[i] = 0.0f;
        }

        #pragma unroll
        for (int m = 0; m < 16; ++m) {
            float cm = coeff[m];
            #pragma unroll
            for (int i = 0; i < 32; i += 4) {
                float4 c4 = *(const float4*)&CpT[p][m][r0 + i];
                reg[i+0] = fmaf(-c4.x, cm, reg[i+0]);
                reg[i+1] = fmaf(-c4.y, cm, reg[i+1]);
                reg[i+2] = fmaf(-c4.z, cm, reg[i+2]);
                reg[i+3] = fmaf(-c4.w, cm, reg[i+3]);
            }
        }
        if (q == q0) {
            #pragma unroll
            for (int j = 0; j < 16; ++j) reg[kl + j] = coeff[j];
        }
    }

    float* __restrict__ out = QT + b * NMAT;
    #pragma unroll
    for (int i = 0; i < 32; ++i) {
        int r = r0 + i;
        out[r * HALF + c] = 2.0f * reg[i] - (r == c ? 1.0f : 0.0f);
    }
}

// ---------------------------------------------------------------------------
// K2a: rows [0,256) from identity, steps d=0..6.  UNCHANGED (verified,
// ~5 us, per-row matrix choice not block-uniform so the col-parallel trick
// would 4x its Q traffic).
// ---------------------------------------------------------------------------
__global__ __launch_bounds__(256) void path_base(const float* __restrict__ QT,
                                                 const float* __restrict__ ident,
                                                 float* __restrict__ P) {
    __shared__ __align__(16) float vs[2][4][HALF];
    const int t    = threadIdx.x;
    const int rg   = t >> 6;                 // row in block (0..3), one wave each
    const int jj   = (t & 63) << 1;          // 2-col chunk
    const int v    = (blockIdx.x << 2) + rg;
    const int vmax = (blockIdx.x << 2) + 3;

    float2 cv = *(const float2*)&ident[jj];
    *(float2*)&vs[0][rg][jj] = cv;
    __syncthreads();

    int cur = 0;
    for (int d = 0; d < 8; ++d) {
        if ((vmax >> (d + 1)) == 0) break;           // block-uniform
        const bool valid = (v >> (d + 1)) > 0;
        const float* __restrict__ Qm = QT + (((v >> d) & 1) ? NMAT : 0);
        float2 acc = make_float2(0.f, 0.f);
        #pragma unroll 4
        for (int cc = 0; cc < 128; cc += 4) {
            float4 v4 = *(const float4*)&vs[cur][rg][cc];
            float2 q0 = *(const float2*)&Qm[(cc+0)*HALF + jj];
            float2 q1 = *(const float2*)&Qm[(cc+1)*HALF + jj];
            float2 q2 = *(const float2*)&Qm[(cc+2)*HALF + jj];
            float2 q3 = *(const float2*)&Qm[(cc+3)*HALF + jj];
            acc.x = fmaf(v4.x,q0.x, fmaf(v4.y,q1.x, fmaf(v4.z,q2.x, fmaf(v4.w,q3.x, acc.x))));
            acc.y = fmaf(v4.x,q0.y, fmaf(v4.y,q1.y, fmaf(v4.z,q2.y, fmaf(v4.w,q3.y, acc.y))));
        }
        if (valid) cv = acc;
        *(float2*)&vs[cur ^ 1][rg][jj] = cv;
        __syncthreads();
        cur ^= 1;
    }
    *(float2*)&P[v * HALF + jj] = cv;
}

// ---------------------------------------------------------------------------
// K2b: rows [256,4096), k-grouped, now COLUMN-PARALLEL:
//   thread (j = t&127, h = t>>7) owns output column j for rows h*4..h*4+3.
//   Q[c][j] comes straight from global (coalesced dword, L1/L2-served; each
//   element read by only 2 threads -> 200 MB L2 total, ~6 us overlapped).
//   Row vector comes from an 8 KB LDS buffer via same-address b128 BROADCASTS
//   (conflict-free, data-trivial).  LDS traffic per block-step: 512 KB -> 8 KB.
//   fma association per output element is bit-identical to the previous
//   verified kernel (ascending-cc chunks, same nested-fmaf order).
// ---------------------------------------------------------------------------
__global__ __launch_bounds__(256) void path_upper(const float* __restrict__ QT,
                                                  float* __restrict__ P) {
    __shared__ __align__(16) float vs[2][8][HALF];   // double-buffered row vals
    const int t  = threadIdx.x;
    const int j  = t & 127;                // owned output column
    const int h  = t >> 7;                 // row half: rows h*4 .. h*4+3
    const int k  = 2 + (blockIdx.x >> 4);  // 30 k-values x 16 blocks = 480
    const int r0 = (blockIdx.x & 15) << 3; // 8 residues per block

    // ancestor rows 128 + r0 + h*4 + rr (written by path_base), column j
    float acc[4];
    #pragma unroll
    for (int rr = 0; rr < 4; ++rr)
        acc[rr] = P[(128 + r0 + h * 4 + rr) * HALF + j];

    int p = 0;
    for (int d = 7; d < 13; ++d) {
        if ((k >> (d - 6)) == 0) break;              // block-uniform
        const float* __restrict__ Qm = QT + (((k >> (d - 7)) & 1) ? NMAT : 0);
        // publish current row values (coalesced b32 writes, conflict-free)
        #pragma unroll
        for (int rr = 0; rr < 4; ++rr) vs[p][h * 4 + rr][j] = acc[rr];
        __syncthreads();                             // other buffer still live

        float nacc[4] = {0.f, 0.f, 0.f, 0.f};
        #pragma unroll 4
        for (int cc = 0; cc < 128; cc += 4) {
            float q0 = Qm[(cc + 0) * HALF + j];      // coalesced global dword
            float q1 = Qm[(cc + 1) * HALF + j];
            float q2 = Qm[(cc + 2) * HALF + j];
            float q3 = Qm[(cc + 3) * HALF + j];
            #pragma unroll
            for (int rr = 0; rr < 4; ++rr) {
                float4 v4 = *(const float4*)&vs[p][h * 4 + rr][cc];  // broadcast
                nacc[rr] = fmaf(v4.x, q0,
                           fmaf(v4.y, q1,
                           fmaf(v4.z, q2,
                           fmaf(v4.w, q3, nacc[rr]))));
            }
        }
        #pragma unroll
        for (int rr = 0; rr < 4; ++rr) acc[rr] = nacc[rr];
        p ^= 1;                                      // next step: other buffer
    }

    #pragma unroll
    for (int rr = 0; rr < 4; ++rr)
        P[((k << 7) | (r0 + h * 4 + rr)) * HALF + j] = acc[rr];
}

// ---------------------------------------------------------------------------
// K3: emit [B,S,256] = content ++ pos.  UNCHANGED (at ~21 us write floor;
// nontemporal stores keep P hot in L2 for the gathers).
// ---------------------------------------------------------------------------
__global__ __launch_bounds__(256) void emit_out(const int* __restrict__ tt,
                                                const int* __restrict__ tv,
                                                const int* __restrict__ np,
                                                const float* __restrict__ P,
                                                const float* __restrict__ emb,
                                                float* __restrict__ out) {
    const int i  = (blockIdx.x << 2) + (threadIdx.x >> 6);
    const int jj = (threadIdx.x & 63) << 2;
    const int ty = tt[i];
    const int v  = tv[i];
    f4 val;
    if (jj < 128) {
        if (ty == 0)      val = *(const f4*)&emb[jj];
        else if (ty == 1) val = *(const f4*)&emb[(v + 1) * HALF + jj];
        else if (ty == 2) val = *(const f4*)&emb[(v + 5) * HALF + jj];
        else if (ty == 4) {
            int vc = v < 0 ? 0 : (v > 4095 ? 4095 : v);
            val = *(const f4*)&P[vc * HALF + jj];
        } else if (v == -1) val = *(const f4*)&emb[10 * HALF + jj];
        else { f4 z = {0.f, 0.f, 0.f, 0.f}; val = z; }
    } else {
        const int p = np[i];
        val = *(const f4*)&P[p * HALF + (jj - 128)];
    }
    __builtin_nontemporal_store(val, (f4*)&out[i * 256 + jj]);
}

extern "C" void kernel_launch(void* const* d_in, const int* in_sizes, int n_in,
                              void* d_out, int out_size, void* d_ws, size_t ws_size,
                              hipStream_t stream) {
    const int*   token_types = (const int*)  d_in[0];
    const int*   token_vals  = (const int*)  d_in[1];
    const int*   node_pos    = (const int*)  d_in[2];
    const float* prim        = (const float*)d_in[3];
    const float* ident       = (const float*)d_in[4];
    const float* emb         = (const float*)d_in[5];
    float* out = (float*)d_out;

    // workspace: QT[2][128][128] | (gap) | P[4096][128]
    float* QT = (float*)d_ws;
    float* P  = (float*)((char*)d_ws + 262144);

    cayley_qt  <<<2,   512, 0, stream>>>(prim, QT);
    path_base  <<<64,  256, 0, stream>>>(QT, ident, P);     // rows [0,256)
    path_upper <<<480, 256, 0, stream>>>(QT, P);            // rows [256,4096)
    emit_out   <<<NTOK / 4, 256, 0, stream>>>(token_types, token_vals, node_pos,
                                              P, emb, out);
}